// Round 1
// baseline (926.125 us; speedup 1.0000x reference)
//
#include <hip/hip_runtime.h>

// ---------------- constants ----------------
#define B_    64
#define CIN   64
#define CH    256
#define T_    2048
#define NP    10
#define INVLN2 1.44269504088896340736f
#define INFV  1e10f
#define WIN   144   // 128-col chunk + 16-col pad

// d_out element offsets (float32)
static const size_t DO_H   = 0;
static const size_t DO_OUT = 33554432;
static const size_t DO_ENS = 33555072;
static const size_t DO_ONE = 34046592;
static const size_t DO_OP  = 34210432;
static const size_t DO_ATT = 34210433;

// d_ws element offsets (float32)
static const size_t OFF_D2 = 0;         // [64][2048][16]
static const size_t OFF_Y  = 2097152;   // [64][2048][16]
static const size_t OFF_A  = 4194304;   // [64][2048][16]
static const size_t OFF_RS = 6291456;   // [64][16]
static const size_t OFF_O1 = 6292480;   // [64][256]
static const size_t OFF_O2 = 6308864;   // [64][256][10]
static const size_t OFF_O3 = 6472704;   // [64][256][10]  (memset from here)
static const size_t OFF_IND= 6636544;   // [0]=ind sum, [1]=op float
static const size_t OFF_Z1 = 6636560;   // [64][512]
static const size_t OFF_Z2 = 6669328;   // [64][1024]
static const size_t WS_END = 6734864;

__device__ __forceinline__ float dpp_shr1(float x) { // lane i <- lane i-1 (16-lane rows), 0-fill
  return __int_as_float(__builtin_amdgcn_update_dpp(0, __float_as_int(x), 0x111, 0xf, 0xf, true));
}
__device__ __forceinline__ float dpp_shl1(float x) { // lane i <- lane i+1 (16-lane rows), 0-fill
  return __int_as_float(__builtin_amdgcn_update_dpp(0, __float_as_int(x), 0x101, 0xf, 0xf, true));
}

// ---------------- K1: h = relu(conv_w @ x + b) ----------------
__global__ __launch_bounds__(256) void k1_conv(const float* __restrict__ x, const float* __restrict__ w,
                                               const float* __restrict__ bias, float* __restrict__ h) {
  const int tt = blockIdx.x, ot = blockIdx.y, b = blockIdx.z;
  const int tid = threadIdx.x;
  __shared__ float xs[64][132];
  __shared__ float wt[64][64];   // transposed [c][o]
  const int t0 = tt * 128, o0 = ot * 64;
  {
    const float* xb = x + ((size_t)b * CIN) * T_ + t0;
#pragma unroll
    for (int k = 0; k < 8; ++k) {
      int idx = tid + k * 256;           // float4 index over 64x128
      int c = idx >> 5, q = idx & 31;
      float4 v = *(const float4*)(xb + (size_t)c * T_ + q * 4);
      *(float4*)(&xs[c][q * 4]) = v;
    }
#pragma unroll
    for (int k = 0; k < 4; ++k) {
      int idx = tid + k * 256;           // float4 index over 64x64
      int o = idx >> 4, c4 = (idx & 15) * 4;
      float4 v = *(const float4*)(w + (size_t)(o0 + o) * 64 + c4);
      wt[c4 + 0][o] = v.x; wt[c4 + 1][o] = v.y; wt[c4 + 2][o] = v.z; wt[c4 + 3][o] = v.w;
    }
  }
  __syncthreads();
  const int og = tid >> 4, tg = tid & 15;
  float acc[4][8];
#pragma unroll
  for (int i = 0; i < 4; ++i)
#pragma unroll
    for (int j = 0; j < 8; ++j) acc[i][j] = 0.f;
  for (int c = 0; c < 64; ++c) {
    float a0 = wt[c][og * 4 + 0], a1 = wt[c][og * 4 + 1], a2 = wt[c][og * 4 + 2], a3 = wt[c][og * 4 + 3];
    float xv[8];
#pragma unroll
    for (int j = 0; j < 8; ++j) xv[j] = xs[c][tg * 8 + j];
#pragma unroll
    for (int j = 0; j < 8; ++j) {
      acc[0][j] += a0 * xv[j]; acc[1][j] += a1 * xv[j];
      acc[2][j] += a2 * xv[j]; acc[3][j] += a3 * xv[j];
    }
  }
  float* hb = h + ((size_t)b * CH + o0) * T_ + t0;
#pragma unroll
  for (int i = 0; i < 4; ++i) {
    const float bv = bias[o0 + og * 4 + i];
    float4 v0, v1;
    v0.x = fmaxf(acc[i][0] + bv, 0.f); v0.y = fmaxf(acc[i][1] + bv, 0.f);
    v0.z = fmaxf(acc[i][2] + bv, 0.f); v0.w = fmaxf(acc[i][3] + bv, 0.f);
    v1.x = fmaxf(acc[i][4] + bv, 0.f); v1.y = fmaxf(acc[i][5] + bv, 0.f);
    v1.z = fmaxf(acc[i][6] + bv, 0.f); v1.w = fmaxf(acc[i][7] + bv, 0.f);
    *(float4*)(&hb[(size_t)(og * 4 + i) * T_ + tg * 8]) = v0;
    *(float4*)(&hb[(size_t)(og * 4 + i) * T_ + tg * 8 + 4]) = v1;
  }
}

// ---------------- K2: D2[b][t][p] = (pn[p] + hn[t] - 2*PH[p,t]) / ln2 ----------------
__global__ __launch_bounds__(256) void k2_d2(const float* __restrict__ h, const float* __restrict__ protos,
                                             float* __restrict__ D2g) {
  const int tt = blockIdx.x, b = blockIdx.y, tid = threadIdx.x;
  __shared__ float pl[2560];
  __shared__ float pn[NP];
#pragma unroll
  for (int k = 0; k < 10; ++k) pl[tid + k * 256] = protos[tid + k * 256];
  __syncthreads();
  if (tid < NP) {
    float s = 0.f;
    for (int c = 0; c < CH; ++c) { float v = pl[c * NP + tid]; s += v * v; }
    pn[tid] = s;
  }
  __syncthreads();
  const int t = tt * 256 + tid;
  const float* hb = h + (size_t)b * CH * T_ + t;
  float hn = 0.f, ph[NP];
#pragma unroll
  for (int p = 0; p < NP; ++p) ph[p] = 0.f;
  for (int c = 0; c < CH; ++c) {
    float hv = hb[(size_t)c * T_];
    hn += hv * hv;
#pragma unroll
    for (int p = 0; p < NP; ++p) ph[p] += pl[c * NP + p] * hv;
  }
  float dv[16];
#pragma unroll
  for (int p = 0; p < NP; ++p) dv[p] = (pn[p] + hn - 2.f * ph[p]) * INVLN2;
#pragma unroll
  for (int p = NP; p < 16; ++p) dv[p] = 0.f;
  float* dst = D2g + ((size_t)b * T_ + t) * 16;
#pragma unroll
  for (int q = 0; q < 4; ++q) {
    float4 v; v.x = dv[q*4]; v.y = dv[q*4+1]; v.z = dv[q*4+2]; v.w = dv[q*4+3];
    *(float4*)(dst + q * 4) = v;
  }
}

// ---------------- K3a: raw segment sums -> out2w ----------------
__global__ __launch_bounds__(64) void k3a_seg(const float* __restrict__ h, float* __restrict__ out2w) {
  const int s = blockIdx.x, o = blockIdx.y, b = blockIdx.z;
  const int lane = threadIdx.x;
  const int base = s * 204;
  const int len = (s == 9) ? 212 : 204;
  const float* hb = h + ((size_t)(b * CH + o)) * T_ + base;
  float v = 0.f;
#pragma unroll
  for (int k = 0; k < 4; ++k) {
    const int idx = lane + k * 64;
    if (idx < len) v += hb[idx];
  }
#pragma unroll
  for (int st = 32; st >= 1; st >>= 1) v += __shfl_xor(v, st);
  if (lane == 0) out2w[((size_t)(b * CH + o)) * NP + s] = v;
}

// ---------------- K3b: finalize means (out1 from segment sums) ----------------
__global__ __launch_bounds__(256) void k3b_fin(float* __restrict__ out2w, float* __restrict__ out1w) {
  const int b = blockIdx.x, o = threadIdx.x;
  float* p = out2w + ((size_t)(b * CH + o)) * NP;
  float vals[NP], tot = 0.f;
#pragma unroll
  for (int s = 0; s < NP; ++s) { vals[s] = p[s]; tot += vals[s]; }
  out1w[b * CH + o] = tot * (1.f / 2048.f);
#pragma unroll
  for (int s = 0; s < 9; ++s) p[s] = vals[s] * (1.f / 204.f);
  p[9] = vals[9] * (1.f / 212.f);
}

// ---------------- K4: soft-DTW forward + backward (one wave per batch) ----------------
__global__ __launch_bounds__(64) void k4_dp(const float* __restrict__ D2g, float* __restrict__ Yg,
                                            float* __restrict__ Ag, float* __restrict__ rowsumg) {
  const int b = blockIdx.x;
  const int lane = threadIdx.x;
  const float* D2b = D2g + (size_t)b * T_ * 16;
  float* Yb = Yg + (size_t)b * T_ * 16;
  float* Ab = Ag + (size_t)b * T_ * 16;
  __shared__ float sD2[2][WIN * 16];
  __shared__ float sY[2][WIN * 16];
  float4 stgD[9], stgY[9];

  // ================= forward =================
  {
#pragma unroll
    for (int i = 0; i < 9; ++i) {
      int off = (-16 * 16) + i * 256 + lane * 4;
      off = off < 0 ? 0 : off;
      stgD[i] = *(const float4*)(D2b + off);
    }
#pragma unroll
    for (int i = 0; i < 9; ++i) *(float4*)(&sD2[0][i * 256 + lane * 4]) = stgD[i];
    __syncthreads();

    float y1 = INFV, y2 = INFV;
#pragma unroll 1
    for (int r = 0; r <= 16; ++r) {
      const int rw = r < 16 ? r : 15;
      const int wbuf = rw & 1;
      const int base_col = 128 * rw - 16;
      const int pref = (r + 1 <= 15) ? (r + 1) : -1;
      if (pref >= 0) {
        const int startf = (128 * pref - 16) * 16;
#pragma unroll
        for (int i = 0; i < 9; ++i) {
          int off = startf + i * 256 + lane * 4;
          stgD[i] = *(const float4*)(D2b + off);
        }
      }
      const int dlo = 128 * r;
      const int dhi = (r == 16) ? (dlo + 16) : (dlo + 128);
#pragma unroll 1
      for (int d0 = dlo; d0 < dhi; d0 += 8) {
        float d2v[8];
#pragma unroll
        for (int j = 0; j < 8; ++j) {
          int t = d0 + j - lane;
          int row = t - base_col;
          row = row < 0 ? 0 : (row > WIN - 1 ? WIN - 1 : row);
          d2v[j] = sD2[wbuf][row * 16 + (lane & 15)];
        }
#pragma unroll
        for (int j = 0; j < 8; ++j) {
          const int d = d0 + j;
          const int t = d - lane;
          float a = dpp_shr1(y1);
          float c = dpp_shr1(y2);
          if (lane == 0) { a = INFV; c = (d == 0) ? 0.f : INFV; }
          const float bb = y1;
          float m = fminf(fminf(a, bb), c);
          float e = __builtin_amdgcn_exp2f(m - a) + __builtin_amdgcn_exp2f(m - bb) +
                    __builtin_amdgcn_exp2f(m - c);
          float yn = d2v[j] + m - __builtin_amdgcn_logf(e);
          const bool valid = (lane < NP) && (t >= 0) && (t < T_);
          yn = valid ? yn : INFV;
          if (valid) Yb[t * 16 + lane] = yn;
          y2 = y1; y1 = yn;
        }
      }
      if (pref >= 0) {
#pragma unroll
        for (int i = 0; i < 9; ++i) *(float4*)(&sD2[pref & 1][i * 256 + lane * 4]) = stgD[i];
        __syncthreads();
      }
    }
  }

  asm volatile("s_waitcnt vmcnt(0)" ::: "memory");
  __syncthreads();

  // ================= backward =================
  {
    const int startf = (128 * 15 - 16) * 16;
#pragma unroll
    for (int i = 0; i < 9; ++i) {
      int off = startf + i * 256 + lane * 4;
      stgD[i] = *(const float4*)(D2b + off);
      stgY[i] = *(const float4*)(Yb + off);
    }
#pragma unroll
    for (int i = 0; i < 9; ++i) {
      *(float4*)(&sD2[1][i * 256 + lane * 4]) = stgD[i];
      *(float4*)(&sY[1][i * 256 + lane * 4]) = stgY[i];
    }
    __syncthreads();

    float E1 = 0.f, E2 = 0.f;
    float yL1 = INFV, yL2 = INFV, dL1 = 0.f, dL2 = 0.f;
    float rsum = 0.f;
#pragma unroll 1
    for (int r = 16; r >= 0; --r) {
      const int rw = r < 16 ? r : 15;
      const int wbuf = rw & 1;
      const int base_col = 128 * rw - 16;
      const int pref = (r == 16) ? 14 : ((r <= 14 && r >= 1) ? r - 1 : -1);
      if (pref >= 0) {
        const int pstart = (128 * pref - 16) * 16;
#pragma unroll
        for (int i = 0; i < 9; ++i) {
          int off = pstart + i * 256 + lane * 4;
          off = off < 0 ? 0 : off;
          stgD[i] = *(const float4*)(D2b + off);
          stgY[i] = *(const float4*)(Yb + off);
        }
      }
      const int dlo = 128 * r;
      const int top = (r == 16) ? (dlo + 15) : (dlo + 127);
#pragma unroll 1
      for (int d0 = top; d0 >= dlo; d0 -= 8) {
        float dvv[8], yv[8];
#pragma unroll
        for (int j = 0; j < 8; ++j) {
          int t = d0 - j - lane;
          int row = t - base_col;
          row = row < 0 ? 0 : (row > WIN - 1 ? WIN - 1 : row);
          dvv[j] = sD2[wbuf][row * 16 + (lane & 15)];
          yv[j] = sY[wbuf][row * 16 + (lane & 15)];
        }
#pragma unroll
        for (int j = 0; j < 8; ++j) {
          const int d = d0 - j;
          const int t = d - lane;
          const float yld = yv[j], dld = dvv[j];
          const float y_dn1 = dpp_shl1(yL1), d_dn1 = dpp_shl1(dL1);
          const float y_dn2 = dpp_shl1(yL2), d_dn2 = dpp_shl1(dL2);
          const float E_dn1 = dpp_shl1(E1), E_dn2 = dpp_shl1(E2);
          float g1 = fminf(y_dn1 - d_dn1 - yld, 0.f);
          float g2 = fminf(yL1 - dL1 - yld, 0.f);
          float g3 = fminf(y_dn2 - d_dn2 - yld, 0.f);
          float En = __builtin_amdgcn_exp2f(g1) * E_dn1 + __builtin_amdgcn_exp2f(g2) * E1 +
                     __builtin_amdgcn_exp2f(g3) * E_dn2;
          const bool valid = (lane < NP) && (t >= 0) && (t < T_);
          if (d == NP + T_ - 2 && lane == NP - 1) En = 1.f;
          En = valid ? En : 0.f;
          if (valid) Ab[t * 16 + lane] = En;
          rsum += En;
          E2 = E1; E1 = En;
          yL2 = yL1; yL1 = yld;
          dL2 = dL1; dL1 = dld;
        }
      }
      if (pref >= 0) {
#pragma unroll
        for (int i = 0; i < 9; ++i) {
          *(float4*)(&sD2[pref & 1][i * 256 + lane * 4]) = stgD[i];
          *(float4*)(&sY[pref & 1][i * 256 + lane * 4]) = stgY[i];
        }
        __syncthreads();
      }
    }
    if (lane < NP) rowsumg[b * 16 + lane] = rsum;
  }
}

// ---------------- K5: out3raw[b,c,p] += sum_t h[b,c,t]*E[b,p,t] ----------------
__global__ __launch_bounds__(256) void k5_out3(const float* __restrict__ h, const float* __restrict__ Ag,
                                               float* __restrict__ out3raw) {
  const int tc = blockIdx.x, b = blockIdx.y, tid = threadIdx.x;
  __shared__ float As[128 * 16];
  const float* Ab = Ag + ((size_t)b * T_ + tc * 128) * 16;
#pragma unroll
  for (int k = 0; k < 2; ++k) {
    int i4 = tid + k * 256;
    *(float4*)(&As[i4 * 4]) = *(const float4*)(Ab + i4 * 4);
  }
  __syncthreads();
  const int c = tid;
  const float* hb = h + ((size_t)b * CH + c) * T_ + tc * 128;
  float acc[NP];
#pragma unroll
  for (int p = 0; p < NP; ++p) acc[p] = 0.f;
  for (int t4 = 0; t4 < 32; ++t4) {
    float4 hv = *(const float4*)(hb + t4 * 4);
    float he[4] = {hv.x, hv.y, hv.z, hv.w};
#pragma unroll
    for (int u = 0; u < 4; ++u) {
      const float* ar = &As[(t4 * 4 + u) * 16];
#pragma unroll
      for (int p = 0; p < NP; ++p) acc[p] += he[u] * ar[p];
    }
  }
  float* dst = out3raw + ((size_t)(b * CH + c)) * NP;
#pragma unroll
  for (int p = 0; p < NP; ++p) atomicAdd(dst + p, acc[p]);
}

// ---------------- K6a: proj, attn softmax, ind argmax ----------------
__global__ __launch_bounds__(64) void k6a_head(const float* __restrict__ out1w, const float* __restrict__ out2w,
                                               const float* __restrict__ out3raw, const float* __restrict__ rowsumg,
                                               const float* __restrict__ enc_w, const float* __restrict__ enc_b,
                                               const float* __restrict__ sw, float* __restrict__ attn_out,
                                               float* __restrict__ ind_sum) {
  const int b = blockIdx.x;
  const int lane = threadIdx.x;
  float a1 = 0.f, a2[NP], a3[NP];
#pragma unroll
  for (int p = 0; p < NP; ++p) { a2[p] = 0.f; a3[p] = 0.f; }
#pragma unroll
  for (int k = 0; k < 4; ++k) {
    const int c = lane + k * 64;
    const float ew = enc_w[c];
    a1 += out1w[b * CH + c] * ew;
    const float* o2 = out2w + ((size_t)(b * CH + c)) * NP;
    const float* o3 = out3raw + ((size_t)(b * CH + c)) * NP;
#pragma unroll
    for (int p = 0; p < NP; ++p) { a2[p] += o2[p] * ew; a3[p] += o3[p] * ew; }
  }
#pragma unroll
  for (int st = 32; st >= 1; st >>= 1) {
    a1 += __shfl_xor(a1, st);
#pragma unroll
    for (int p = 0; p < NP; ++p) { a2[p] += __shfl_xor(a2[p], st); a3[p] += __shfl_xor(a3[p], st); }
  }
  __shared__ float proj[30];
  __shared__ float indv[90];
  if (lane == 0) {
#pragma unroll
    for (int p = 0; p < NP; ++p) {
      proj[p] = a1;
      proj[10 + p] = a2[p];
      proj[20 + p] = a3[p] / rowsumg[b * 16 + p];
    }
  }
  __syncthreads();
  if (lane < 30) {
    const float pj = proj[lane];
    const float eb = enc_b[0];
    float lg[30];
    float mx = -1e30f;
#pragma unroll
    for (int j = 0; j < 30; ++j) { lg[j] = pj * sw[j] + eb; mx = fmaxf(mx, lg[j]); }
    float ssum = 0.f;
#pragma unroll
    for (int j = 0; j < 30; ++j) { lg[j] = expf(lg[j] - mx); ssum += lg[j]; }
    const float inv = 1.f / ssum;
    float m0 = 0.f, m1 = 0.f, m2 = 0.f;
#pragma unroll
    for (int j = 0; j < 30; ++j) {
      const float av = lg[j] * inv;
      attn_out[(size_t)b * 900 + lane * 30 + j] = av;
      if (j < 10) m0 += av; else if (j < 20) m1 += av; else m2 += av;
    }
    indv[lane] = m0 * 0.1f; indv[30 + lane] = m1 * 0.1f; indv[60 + lane] = m2 * 0.1f;
  }
  __syncthreads();
  if (lane == 0) {
    float best = -1e30f; int bi = 0;
    for (int k = 0; k < 90; ++k) { const float v = indv[k]; if (v > best) { best = v; bi = k; } }
    atomicAdd(ind_sum, (float)bi);
  }
}

// ---------------- K6b: op scalar ----------------
__global__ void k6b_op(float* __restrict__ ind_sum, float* __restrict__ op_out) {
  const float ind = ind_sum[0] * (1.f / 64.f);
  const int op = ind < 0.6f ? 0 : (ind < 1.6f ? 1 : 2);
  ind_sum[1] = (float)op;
  op_out[0] = (float)op;
}

// ---------------- K7a: one = selected branch ----------------
__global__ __launch_bounds__(256) void k7a_one(const float* __restrict__ out1w, const float* __restrict__ out2w,
                                               const float* __restrict__ out3raw, const float* __restrict__ rowsumg,
                                               const float* __restrict__ indws, float* __restrict__ one_out) {
  const int b = blockIdx.x, c = threadIdx.x;
  const int op = (int)indws[1];
  float* dst = one_out + ((size_t)(b * CH + c)) * NP;
  if (op == 0) {
    const float v = out1w[b * CH + c];
#pragma unroll
    for (int p = 0; p < NP; ++p) dst[p] = v;
  } else if (op == 1) {
    const float* s = out2w + ((size_t)(b * CH + c)) * NP;
#pragma unroll
    for (int p = 0; p < NP; ++p) dst[p] = s[p];
  } else {
    const float* s = out3raw + ((size_t)(b * CH + c)) * NP;
#pragma unroll
    for (int p = 0; p < NP; ++p) dst[p] = s[p] / rowsumg[b * 16 + p];
  }
}

// ---------------- K7b: ensemble = concat_out @ attn ----------------
__global__ __launch_bounds__(256) void k7b_ens(const float* __restrict__ out1w, const float* __restrict__ out2w,
                                               const float* __restrict__ out3raw, const float* __restrict__ rowsumg,
                                               const float* __restrict__ attn, float* __restrict__ ens) {
  const int b = blockIdx.x, tid = threadIdx.x;
  __shared__ float at[900];
  __shared__ float s0[30];
  __shared__ float irs[NP];
  for (int k = tid; k < 900; k += 256) at[k] = attn[(size_t)b * 900 + k];
  if (tid < NP) irs[tid] = 1.f / rowsumg[b * 16 + tid];
  __syncthreads();
  if (tid < 30) {
    float s = 0.f;
    for (int i = 0; i < 10; ++i) s += at[i * 30 + tid];
    s0[tid] = s;
  }
  __syncthreads();
  const int c = tid;
  const float o1 = out1w[b * CH + c];
  float o2[NP], o3[NP];
  const float* p2 = out2w + ((size_t)(b * CH + c)) * NP;
  const float* p3 = out3raw + ((size_t)(b * CH + c)) * NP;
#pragma unroll
  for (int p = 0; p < NP; ++p) { o2[p] = p2[p]; o3[p] = p3[p] * irs[p]; }
  float* dst = ens + ((size_t)(b * CH + c)) * 30;
#pragma unroll
  for (int j = 0; j < 30; ++j) {
    float acc = o1 * s0[j];
#pragma unroll
    for (int p = 0; p < NP; ++p) acc += o2[p] * at[(10 + p) * 30 + j] + o3[p] * at[(20 + p) * 30 + j];
    dst[j] = acc;
  }
}

// ---------------- K7c: z1 partial GEMM (one[64x2560] @ w1^T -> [64x512]) ----------------
__global__ __launch_bounds__(256) void k7c_z1(const float* __restrict__ one_, const float* __restrict__ w1,
                                              float* __restrict__ z1acc) {
  const int kt = blockIdx.x;  // 8
  const int mt = blockIdx.y;  // 40
  const int tid = threadIdx.x;
  __shared__ float os[64][65];
  __shared__ float wsl[64][65];
  const int k0 = kt * 64, m0 = mt * 64;
#pragma unroll
  for (int k = 0; k < 4; ++k) {
    int idx = tid + k * 256;
    int r = idx >> 4, q = (idx & 15) * 4;
    float4 v1 = *(const float4*)(one_ + (size_t)r * 2560 + m0 + q);
    os[r][q] = v1.x; os[r][q + 1] = v1.y; os[r][q + 2] = v1.z; os[r][q + 3] = v1.w;
    float4 v2 = *(const float4*)(w1 + (size_t)(k0 + r) * 2560 + m0 + q);
    wsl[r][q] = v2.x; wsl[r][q + 1] = v2.y; wsl[r][q + 2] = v2.z; wsl[r][q + 3] = v2.w;
  }
  __syncthreads();
  const int bg = tid >> 4, kg = tid & 15;
  float acc[4][4];
#pragma unroll
  for (int i = 0; i < 4; ++i)
#pragma unroll
    for (int j = 0; j < 4; ++j) acc[i][j] = 0.f;
  for (int m = 0; m < 64; ++m) {
    float ov[4], wv[4];
#pragma unroll
    for (int i = 0; i < 4; ++i) { ov[i] = os[bg * 4 + i][m]; wv[i] = wsl[kg * 4 + i][m]; }
#pragma unroll
    for (int i = 0; i < 4; ++i)
#pragma unroll
      for (int j = 0; j < 4; ++j) acc[i][j] += ov[i] * wv[j];
  }
#pragma unroll
  for (int i = 0; i < 4; ++i)
#pragma unroll
    for (int j = 0; j < 4; ++j)
      atomicAdd(&z1acc[(size_t)(bg * 4 + i) * 512 + k0 + kg * 4 + j], acc[i][j]);
}

// ---------------- K7d: z2 partial GEMM (relu(z1+b1)[64x512] @ w2^T -> [64x1024]) ----------------
__global__ __launch_bounds__(256) void k7d_z2(const float* __restrict__ z1acc, const float* __restrict__ db1,
                                              const float* __restrict__ w2, float* __restrict__ z2acc) {
  const int kt = blockIdx.x;  // 16
  const int mt = blockIdx.y;  // 8
  const int tid = threadIdx.x;
  __shared__ float os[64][65];
  __shared__ float wsl[64][65];
  const int k0 = kt * 64, m0 = mt * 64;
#pragma unroll
  for (int k = 0; k < 4; ++k) {
    int idx = tid + k * 256;
    int r = idx >> 4, q = (idx & 15) * 4;
    float4 v1 = *(const float4*)(z1acc + (size_t)r * 512 + m0 + q);
    float4 bv = *(const float4*)(db1 + m0 + q);
    os[r][q] = fmaxf(v1.x + bv.x, 0.f); os[r][q + 1] = fmaxf(v1.y + bv.y, 0.f);
    os[r][q + 2] = fmaxf(v1.z + bv.z, 0.f); os[r][q + 3] = fmaxf(v1.w + bv.w, 0.f);
    float4 v2 = *(const float4*)(w2 + (size_t)(k0 + r) * 512 + m0 + q);
    wsl[r][q] = v2.x; wsl[r][q + 1] = v2.y; wsl[r][q + 2] = v2.z; wsl[r][q + 3] = v2.w;
  }
  __syncthreads();
  const int bg = tid >> 4, kg = tid & 15;
  float acc[4][4];
#pragma unroll
  for (int i = 0; i < 4; ++i)
#pragma unroll
    for (int j = 0; j < 4; ++j) acc[i][j] = 0.f;
  for (int m = 0; m < 64; ++m) {
    float ov[4], wv[4];
#pragma unroll
    for (int i = 0; i < 4; ++i) { ov[i] = os[bg * 4 + i][m]; wv[i] = wsl[kg * 4 + i][m]; }
#pragma unroll
    for (int i = 0; i < 4; ++i)
#pragma unroll
      for (int j = 0; j < 4; ++j) acc[i][j] += ov[i] * wv[j];
  }
#pragma unroll
  for (int i = 0; i < 4; ++i)
#pragma unroll
    for (int j = 0; j < 4; ++j)
      atomicAdd(&z2acc[(size_t)(bg * 4 + i) * 1024 + k0 + kg * 4 + j], acc[i][j]);
}

// ---------------- K7e: out = relu(z2+b2) @ w3^T + b3 ----------------
__global__ __launch_bounds__(64) void k7e_out(const float* __restrict__ z2acc, const float* __restrict__ db2,
                                              const float* __restrict__ w3, const float* __restrict__ db3,
                                              float* __restrict__ outp) {
  const int b = blockIdx.x, lane = threadIdx.x;
  float acc[NP];
#pragma unroll
  for (int n = 0; n < NP; ++n) acc[n] = 0.f;
  for (int j = lane; j < 1024; j += 64) {
    float zv = z2acc[(size_t)b * 1024 + j] + db2[j];
    zv = fmaxf(zv, 0.f);
#pragma unroll
    for (int n = 0; n < NP; ++n) acc[n] += zv * w3[(size_t)n * 1024 + j];
  }
#pragma unroll
  for (int n = 0; n < NP; ++n)
#pragma unroll
    for (int st = 32; st >= 1; st >>= 1) acc[n] += __shfl_xor(acc[n], st);
  if (lane == 0) {
#pragma unroll
    for (int n = 0; n < NP; ++n) outp[b * NP + n] = acc[n] + db3[n];
  }
}

// ---------------- launch ----------------
extern "C" void kernel_launch(void* const* d_in, const int* in_sizes, int n_in,
                              void* d_out, int out_size, void* d_ws, size_t ws_size,
                              hipStream_t stream) {
  (void)in_sizes; (void)n_in; (void)out_size; (void)ws_size;
  const float* x      = (const float*)d_in[0];
  const float* conv_w = (const float*)d_in[1];
  const float* conv_b = (const float*)d_in[2];
  const float* protos = (const float*)d_in[3];
  const float* sw     = (const float*)d_in[4];
  const float* enc_w  = (const float*)d_in[5];
  const float* enc_b  = (const float*)d_in[6];
  const float* dw1    = (const float*)d_in[7];
  const float* db1    = (const float*)d_in[8];
  const float* dw2    = (const float*)d_in[9];
  const float* db2    = (const float*)d_in[10];
  const float* dw3    = (const float*)d_in[11];
  const float* db3    = (const float*)d_in[12];
  float* out = (float*)d_out;
  float* ws  = (float*)d_ws;

  float* D2g     = ws + OFF_D2;
  float* Yg      = ws + OFF_Y;
  float* Ag      = ws + OFF_A;
  float* rowsumg = ws + OFF_RS;
  float* out1w   = ws + OFF_O1;
  float* out2w   = ws + OFF_O2;
  float* out3raw = ws + OFF_O3;
  float* indws   = ws + OFF_IND;
  float* z1acc   = ws + OFF_Z1;
  float* z2acc   = ws + OFF_Z2;
  float* h       = out + DO_H;

  // zero the atomic accumulators (out3raw, ind, z1acc, z2acc)
  hipMemsetAsync(ws + OFF_O3, 0, (WS_END - OFF_O3) * sizeof(float), stream);

  k1_conv<<<dim3(16, 4, 64), 256, 0, stream>>>(x, conv_w, conv_b, h);
  k2_d2<<<dim3(8, 64), 256, 0, stream>>>(h, protos, D2g);
  k3a_seg<<<dim3(10, 256, 64), 64, 0, stream>>>(h, out2w);
  k3b_fin<<<64, 256, 0, stream>>>(out2w, out1w);
  k4_dp<<<64, 64, 0, stream>>>(D2g, Yg, Ag, rowsumg);
  k5_out3<<<dim3(16, 64), 256, 0, stream>>>(h, Ag, out3raw);
  k6a_head<<<64, 64, 0, stream>>>(out1w, out2w, out3raw, rowsumg, enc_w, enc_b, sw,
                                  out + DO_ATT, indws);
  k6b_op<<<1, 1, 0, stream>>>(indws, out + DO_OP);
  k7a_one<<<64, 256, 0, stream>>>(out1w, out2w, out3raw, rowsumg, indws, out + DO_ONE);
  k7b_ens<<<64, 256, 0, stream>>>(out1w, out2w, out3raw, rowsumg, out + DO_ATT, out + DO_ENS);
  k7c_z1<<<dim3(8, 40), 256, 0, stream>>>(out + DO_ONE, dw1, z1acc);
  k7d_z2<<<dim3(16, 8), 256, 0, stream>>>(z1acc, db1, dw2, z2acc);
  k7e_out<<<64, 64, 0, stream>>>(z2acc, db2, dw3, db3, out + DO_OUT);
}

// Round 2
// 872.644 us; speedup vs baseline: 1.0613x; 1.0613x over previous
//
#include <hip/hip_runtime.h>

// ---------------- constants ----------------
#define B_    64
#define CIN   64
#define CH    256
#define T_    2048
#define NP    10
#define INVLN2 1.44269504088896340736f
#define INFV  1e10f
#define TPAD  2064   // 2048 rows + 16 dump rows for DP boundary spill

// d_out element offsets (float32)
static const size_t DO_H   = 0;
static const size_t DO_OUT = 33554432;
static const size_t DO_ENS = 33555072;
static const size_t DO_ONE = 34046592;
static const size_t DO_OP  = 34210432;
static const size_t DO_ATT = 34210433;

// d_ws element offsets (float32)
static const size_t OFF_D2 = 0;         // [64][2064][16]
static const size_t OFF_Y  = 2113536;   // [64][2064][16]
static const size_t OFF_A  = 4227072;   // [64][2064][16]
static const size_t OFF_RS = 6340608;   // [64][16]
static const size_t OFF_O1 = 6341632;   // [64][256]
static const size_t OFF_O2 = 6358016;   // [64][256][10]
static const size_t OFF_O3 = 6521856;   // [64][256][10]  (memset from here)
static const size_t OFF_IND= 6685696;   // [0]=ind sum, [1]=op float
static const size_t OFF_Z1 = 6685712;   // [64][512]
static const size_t OFF_Z2 = 6718480;   // [64][1024]
static const size_t WS_END = 6784016;

// lane i <- lane i-1 within 16-lane row; invalid lanes get INFV (old operand, bound_ctrl=0)
__device__ __forceinline__ float dpp_shr1_inf(float x) {
  return __int_as_float(__builtin_amdgcn_update_dpp(
      __float_as_int(INFV), __float_as_int(x), 0x111, 0xf, 0xf, false));
}
// lane i <- lane i+1 within 16-lane row; invalid lanes get 0
__device__ __forceinline__ float dpp_shl1_z(float x) {
  return __int_as_float(__builtin_amdgcn_update_dpp(0, __float_as_int(x), 0x101, 0xf, 0xf, true));
}

// ---------------- K1: h = relu(conv_w @ x + b) ----------------
__global__ __launch_bounds__(256) void k1_conv(const float* __restrict__ x, const float* __restrict__ w,
                                               const float* __restrict__ bias, float* __restrict__ h) {
  const int tt = blockIdx.x, ot = blockIdx.y, b = blockIdx.z;
  const int tid = threadIdx.x;
  __shared__ float xs[64][132];
  __shared__ float wt[64][64];   // transposed [c][o]
  const int t0 = tt * 128, o0 = ot * 64;
  {
    const float* xb = x + ((size_t)b * CIN) * T_ + t0;
#pragma unroll
    for (int k = 0; k < 8; ++k) {
      int idx = tid + k * 256;           // float4 index over 64x128
      int c = idx >> 5, q = idx & 31;
      float4 v = *(const float4*)(xb + (size_t)c * T_ + q * 4);
      *(float4*)(&xs[c][q * 4]) = v;
    }
#pragma unroll
    for (int k = 0; k < 4; ++k) {
      int idx = tid + k * 256;           // float4 index over 64x64
      int o = idx >> 4, c4 = (idx & 15) * 4;
      float4 v = *(const float4*)(w + (size_t)(o0 + o) * 64 + c4);
      wt[c4 + 0][o] = v.x; wt[c4 + 1][o] = v.y; wt[c4 + 2][o] = v.z; wt[c4 + 3][o] = v.w;
    }
  }
  __syncthreads();
  const int og = tid >> 4, tg = tid & 15;
  float acc[4][8];
#pragma unroll
  for (int i = 0; i < 4; ++i)
#pragma unroll
    for (int j = 0; j < 8; ++j) acc[i][j] = 0.f;
  for (int c = 0; c < 64; ++c) {
    float a0 = wt[c][og * 4 + 0], a1 = wt[c][og * 4 + 1], a2 = wt[c][og * 4 + 2], a3 = wt[c][og * 4 + 3];
    float xv[8];
#pragma unroll
    for (int j = 0; j < 8; ++j) xv[j] = xs[c][tg * 8 + j];
#pragma unroll
    for (int j = 0; j < 8; ++j) {
      acc[0][j] += a0 * xv[j]; acc[1][j] += a1 * xv[j];
      acc[2][j] += a2 * xv[j]; acc[3][j] += a3 * xv[j];
    }
  }
  float* hb = h + ((size_t)b * CH + o0) * T_ + t0;
#pragma unroll
  for (int i = 0; i < 4; ++i) {
    const float bv = bias[o0 + og * 4 + i];
    float4 v0, v1;
    v0.x = fmaxf(acc[i][0] + bv, 0.f); v0.y = fmaxf(acc[i][1] + bv, 0.f);
    v0.z = fmaxf(acc[i][2] + bv, 0.f); v0.w = fmaxf(acc[i][3] + bv, 0.f);
    v1.x = fmaxf(acc[i][4] + bv, 0.f); v1.y = fmaxf(acc[i][5] + bv, 0.f);
    v1.z = fmaxf(acc[i][6] + bv, 0.f); v1.w = fmaxf(acc[i][7] + bv, 0.f);
    *(float4*)(&hb[(size_t)(og * 4 + i) * T_ + tg * 8]) = v0;
    *(float4*)(&hb[(size_t)(og * 4 + i) * T_ + tg * 8 + 4]) = v1;
  }
}

// ---------------- K2: D2[b][t][p] = (pn[p] + hn[t] - 2*PH[p,t]) / ln2 ----------------
__global__ __launch_bounds__(256) void k2_d2(const float* __restrict__ h, const float* __restrict__ protos,
                                             float* __restrict__ D2g) {
  const int tt = blockIdx.x, b = blockIdx.y, tid = threadIdx.x;
  __shared__ float pl[2560];
  __shared__ float pn[NP];
#pragma unroll
  for (int k = 0; k < 10; ++k) pl[tid + k * 256] = protos[tid + k * 256];
  __syncthreads();
  if (tid < NP) {
    float s = 0.f;
    for (int c = 0; c < CH; ++c) { float v = pl[c * NP + tid]; s += v * v; }
    pn[tid] = s;
  }
  __syncthreads();
  const int t = tt * 256 + tid;
  const float* hb = h + (size_t)b * CH * T_ + t;
  float hn = 0.f, ph[NP];
#pragma unroll
  for (int p = 0; p < NP; ++p) ph[p] = 0.f;
  for (int c = 0; c < CH; ++c) {
    float hv = hb[(size_t)c * T_];
    hn += hv * hv;
#pragma unroll
    for (int p = 0; p < NP; ++p) ph[p] += pl[c * NP + p] * hv;
  }
  float dv[16];
#pragma unroll
  for (int p = 0; p < NP; ++p) dv[p] = (pn[p] + hn - 2.f * ph[p]) * INVLN2;
#pragma unroll
  for (int p = NP; p < 16; ++p) dv[p] = 0.f;
  float* dst = D2g + ((size_t)b * TPAD + t) * 16;
#pragma unroll
  for (int q = 0; q < 4; ++q) {
    float4 v; v.x = dv[q*4]; v.y = dv[q*4+1]; v.z = dv[q*4+2]; v.w = dv[q*4+3];
    *(float4*)(dst + q * 4) = v;
  }
}

// ---------------- K3a: raw segment sums -> out2w ----------------
__global__ __launch_bounds__(64) void k3a_seg(const float* __restrict__ h, float* __restrict__ out2w) {
  const int s = blockIdx.x, o = blockIdx.y, b = blockIdx.z;
  const int lane = threadIdx.x;
  const int base = s * 204;
  const int len = (s == 9) ? 212 : 204;
  const float* hb = h + ((size_t)(b * CH + o)) * T_ + base;
  float v = 0.f;
#pragma unroll
  for (int k = 0; k < 4; ++k) {
    const int idx = lane + k * 64;
    if (idx < len) v += hb[idx];
  }
#pragma unroll
  for (int st = 32; st >= 1; st >>= 1) v += __shfl_xor(v, st);
  if (lane == 0) out2w[((size_t)(b * CH + o)) * NP + s] = v;
}

// ---------------- K3b: finalize means (out1 from segment sums) ----------------
__global__ __launch_bounds__(256) void k3b_fin(float* __restrict__ out2w, float* __restrict__ out1w) {
  const int b = blockIdx.x, o = threadIdx.x;
  float* p = out2w + ((size_t)(b * CH + o)) * NP;
  float vals[NP], tot = 0.f;
#pragma unroll
  for (int s = 0; s < NP; ++s) { vals[s] = p[s]; tot += vals[s]; }
  out1w[b * CH + o] = tot * (1.f / 2048.f);
#pragma unroll
  for (int s = 0; s < 9; ++s) p[s] = vals[s] * (1.f / 204.f);
  p[9] = vals[9] * (1.f / 212.f);
}

// ---------------- K4: soft-DTW forward + backward, register-resident, no LDS ----------------
// One wave per batch; lanes 0-15 active (lane l = prototype row p=l, l>=10 carries benign junk).
// Element offset of cell (p=l, t) in a [TPAD][16] buffer: 16*t + l = 16*d - 15*l, d = t + l.
__global__ __launch_bounds__(64) void k4_dp(const float* __restrict__ D2g, float* __restrict__ Yg,
                                            float* __restrict__ Ag, float* __restrict__ rowsumg) {
  const int b = blockIdx.x;
  const int l = threadIdx.x;
  if (l >= 16) return;                 // uniform exec for the whole DP: no per-store masking
  const float* __restrict__ D2b = D2g + (size_t)b * TPAD * 16;
  float* __restrict__ Yb = Yg + (size_t)b * TPAD * 16;
  float* __restrict__ Ab = Ag + (size_t)b * TPAD * 16;

  // ================= forward =================
  float y1 = INFV, y2 = INFV;          // diagonals d-1, d-2
  {
    // d = 0: only (0,0) valid; R[-1,-1]=0 -> y(0,0) = D2(0,0)
    {
      float d2v = D2b[l];
      float yn = (l == 0) ? d2v : INFV;
      Yb[l] = yn;                      // lanes>0 write INFV into (p=l,t=0); overwritten at d=l
      y2 = y1; y1 = yn;
    }
    // prologue d = 1..15 (masked)
#pragma unroll
    for (int d = 1; d < 16; ++d) {
      int t = d - l;
      int tc = t >= 0 ? t : 0;
      float d2v = D2b[tc * 16 + l];
      float a = dpp_shr1_inf(y1);
      float c = dpp_shr1_inf(y2);
      float m = fminf(fminf(a, y1), c);
      float e = __builtin_amdgcn_exp2f(m - a) + __builtin_amdgcn_exp2f(m - y1)
              + __builtin_amdgcn_exp2f(m - c);
      float yn = d2v + m - __builtin_amdgcn_logf(e);
      yn = (t >= 0) ? yn : INFV;
      Yb[tc * 16 + l] = yn;
      y2 = y1; y1 = yn;
    }
    // main body d = 16..2047: all lanes valid, mask-free, prefetched
    const float* pD = D2b + (16 * 16 - 15 * l);
    float* pY = Yb + (16 * 16 - 15 * l);
    float cur[8];
#pragma unroll
    for (int j = 0; j < 8; ++j) cur[j] = pD[j * 16];
    pD += 128;
#pragma unroll 1
    for (int d0 = 16; d0 < 2048; d0 += 8) {
      float nxt[8];
#pragma unroll
      for (int j = 0; j < 8; ++j) nxt[j] = pD[j * 16];   // over-reads land in padded dump region
      pD += 128;
#pragma unroll
      for (int j = 0; j < 8; ++j) {
        float a = dpp_shr1_inf(y1);
        float c = dpp_shr1_inf(y2);
        float m = fminf(fminf(a, y1), c);
        float e = __builtin_amdgcn_exp2f(m - a) + __builtin_amdgcn_exp2f(m - y1)
                + __builtin_amdgcn_exp2f(m - c);
        float yn = cur[j] + m - __builtin_amdgcn_logf(e);
        pY[j * 16] = yn;
        y2 = y1; y1 = yn;
      }
      pY += 128;
#pragma unroll
      for (int j = 0; j < 8; ++j) cur[j] = nxt[j];
    }
    // epilogue d = 2048..2056 (masked); invalid lanes write INFV into dump rows (t>=2048),
    // which is exactly the boundary value the backward start block reads.
#pragma unroll
    for (int dd = 0; dd < 9; ++dd) {
      int d = 2048 + dd;
      int t = d - l;                   // <= 2056 < TPAD
      float d2v = D2b[t * 16 + l];
      float a = dpp_shr1_inf(y1);
      float c = dpp_shr1_inf(y2);
      float m = fminf(fminf(a, y1), c);
      float e = __builtin_amdgcn_exp2f(m - a) + __builtin_amdgcn_exp2f(m - y1)
              + __builtin_amdgcn_exp2f(m - c);
      float yn = d2v + m - __builtin_amdgcn_logf(e);
      yn = (t < T_) ? yn : INFV;
      Yb[t * 16 + l] = yn;
      y2 = y1; y1 = yn;
    }
  }

  asm volatile("s_waitcnt vmcnt(0)" ::: "memory");   // forward Y stores -> backward Y loads

  // ================= backward =================
  {
    float E1 = 0.f, E2 = 0.f;          // E of diagonals d+1, d+2
    float m1 = 0.f, m2 = 0.f;          // (Y - D2) of diagonals d+1, d+2
    float rsum = 0.f;
    // start block d = 2056..2048 (seed at d=2056, lane 9)
#pragma unroll
    for (int dd = 0; dd < 9; ++dd) {
      int t = (2056 - dd) - l;         // 2033..2056, inside padded region
      float yld = Yb[t * 16 + l];
      float dld = D2b[t * 16 + l];
      float g1 = fminf(dpp_shl1_z(m1) - yld, 0.f);
      float g2 = fminf(m1 - yld, 0.f);
      float g3 = fminf(dpp_shl1_z(m2) - yld, 0.f);
      float En = __builtin_amdgcn_exp2f(g1) * dpp_shl1_z(E1)
               + __builtin_amdgcn_exp2f(g2) * E1
               + __builtin_amdgcn_exp2f(g3) * dpp_shl1_z(E2);
      if (dd == 0) En = (l == 9) ? 1.f : 0.f;
      Ab[t * 16 + l] = En;
      rsum += En;
      E2 = E1; E1 = En; m2 = m1; m1 = yld - dld;
    }
    // main body d = 2047..16, mask-free, prefetched (descending)
    const float* pDr = D2b + (16 * 2047 - 15 * l);
    const float* pYr = Yb + (16 * 2047 - 15 * l);
    float* pAr = Ab + (16 * 2047 - 15 * l);
    float yc[8], dc[8];
#pragma unroll
    for (int j = 0; j < 8; ++j) { yc[j] = pYr[-16 * j]; dc[j] = pDr[-16 * j]; }
    pDr -= 128; pYr -= 128;
#pragma unroll 1
    for (int d0 = 2047; d0 >= 23; d0 -= 8) {
      float yn_[8], dn_[8];
      if (d0 > 30) {                   // next block stays in-bounds only while d0-15 >= 16
#pragma unroll
        for (int j = 0; j < 8; ++j) { yn_[j] = pYr[-16 * j]; dn_[j] = pDr[-16 * j]; }
        pDr -= 128; pYr -= 128;
      }
#pragma unroll
      for (int j = 0; j < 8; ++j) {
        float yld = yc[j], dld = dc[j];
        float g1 = fminf(dpp_shl1_z(m1) - yld, 0.f);
        float g2 = fminf(m1 - yld, 0.f);
        float g3 = fminf(dpp_shl1_z(m2) - yld, 0.f);
        float En = __builtin_amdgcn_exp2f(g1) * dpp_shl1_z(E1)
                 + __builtin_amdgcn_exp2f(g2) * E1
                 + __builtin_amdgcn_exp2f(g3) * dpp_shl1_z(E2);
        pAr[-16 * j] = En;
        rsum += En;
        E2 = E1; E1 = En; m2 = m1; m1 = yld - dld;
      }
      pAr -= 128;
#pragma unroll
      for (int j = 0; j < 8; ++j) { yc[j] = yn_[j]; dc[j] = dn_[j]; }
    }
    // end block d = 15..0 (masked; invalid lanes redirected to dump row 2063, forced 0)
#pragma unroll
    for (int dd = 0; dd < 16; ++dd) {
      int d = 15 - dd;
      int t = d - l;
      int tc = t >= 0 ? t : 2063;
      float yld = Yb[tc * 16 + l];
      float dld = D2b[tc * 16 + l];
      float g1 = fminf(dpp_shl1_z(m1) - yld, 0.f);
      float g2 = fminf(m1 - yld, 0.f);
      float g3 = fminf(dpp_shl1_z(m2) - yld, 0.f);
      float En = __builtin_amdgcn_exp2f(g1) * dpp_shl1_z(E1)
               + __builtin_amdgcn_exp2f(g2) * E1
               + __builtin_amdgcn_exp2f(g3) * dpp_shl1_z(E2);
      En = (t >= 0) ? En : 0.f;
      Ab[tc * 16 + l] = En;
      rsum += En;
      E2 = E1; E1 = En; m2 = m1; m1 = yld - dld;
    }
    if (l < NP) rowsumg[b * 16 + l] = rsum;
  }
}

// ---------------- K5: out3raw[b,c,p] += sum_t h[b,c,t]*E[b,p,t] ----------------
__global__ __launch_bounds__(256) void k5_out3(const float* __restrict__ h, const float* __restrict__ Ag,
                                               float* __restrict__ out3raw) {
  const int tc = blockIdx.x, b = blockIdx.y, tid = threadIdx.x;
  __shared__ float As[128 * 16];
  const float* Ab = Ag + ((size_t)b * TPAD + tc * 128) * 16;
#pragma unroll
  for (int k = 0; k < 2; ++k) {
    int i4 = tid + k * 256;
    *(float4*)(&As[i4 * 4]) = *(const float4*)(Ab + i4 * 4);
  }
  __syncthreads();
  const int c = tid;
  const float* hb = h + ((size_t)b * CH + c) * T_ + tc * 128;
  float acc[NP];
#pragma unroll
  for (int p = 0; p < NP; ++p) acc[p] = 0.f;
  for (int t4 = 0; t4 < 32; ++t4) {
    float4 hv = *(const float4*)(hb + t4 * 4);
    float he[4] = {hv.x, hv.y, hv.z, hv.w};
#pragma unroll
    for (int u = 0; u < 4; ++u) {
      const float* ar = &As[(t4 * 4 + u) * 16];
#pragma unroll
      for (int p = 0; p < NP; ++p) acc[p] += he[u] * ar[p];
    }
  }
  float* dst = out3raw + ((size_t)(b * CH + c)) * NP;
#pragma unroll
  for (int p = 0; p < NP; ++p) atomicAdd(dst + p, acc[p]);
}

// ---------------- K6a: proj, attn softmax, ind argmax ----------------
__global__ __launch_bounds__(64) void k6a_head(const float* __restrict__ out1w, const float* __restrict__ out2w,
                                               const float* __restrict__ out3raw, const float* __restrict__ rowsumg,
                                               const float* __restrict__ enc_w, const float* __restrict__ enc_b,
                                               const float* __restrict__ sw, float* __restrict__ attn_out,
                                               float* __restrict__ ind_sum) {
  const int b = blockIdx.x;
  const int lane = threadIdx.x;
  float a1 = 0.f, a2[NP], a3[NP];
#pragma unroll
  for (int p = 0; p < NP; ++p) { a2[p] = 0.f; a3[p] = 0.f; }
#pragma unroll
  for (int k = 0; k < 4; ++k) {
    const int c = lane + k * 64;
    const float ew = enc_w[c];
    a1 += out1w[b * CH + c] * ew;
    const float* o2 = out2w + ((size_t)(b * CH + c)) * NP;
    const float* o3 = out3raw + ((size_t)(b * CH + c)) * NP;
#pragma unroll
    for (int p = 0; p < NP; ++p) { a2[p] += o2[p] * ew; a3[p] += o3[p] * ew; }
  }
#pragma unroll
  for (int st = 32; st >= 1; st >>= 1) {
    a1 += __shfl_xor(a1, st);
#pragma unroll
    for (int p = 0; p < NP; ++p) { a2[p] += __shfl_xor(a2[p], st); a3[p] += __shfl_xor(a3[p], st); }
  }
  __shared__ float proj[30];
  __shared__ float indv[90];
  if (lane == 0) {
#pragma unroll
    for (int p = 0; p < NP; ++p) {
      proj[p] = a1;
      proj[10 + p] = a2[p];
      proj[20 + p] = a3[p] / rowsumg[b * 16 + p];
    }
  }
  __syncthreads();
  if (lane < 30) {
    const float pj = proj[lane];
    const float eb = enc_b[0];
    float lg[30];
    float mx = -1e30f;
#pragma unroll
    for (int j = 0; j < 30; ++j) { lg[j] = pj * sw[j] + eb; mx = fmaxf(mx, lg[j]); }
    float ssum = 0.f;
#pragma unroll
    for (int j = 0; j < 30; ++j) { lg[j] = expf(lg[j] - mx); ssum += lg[j]; }
    const float inv = 1.f / ssum;
    float m0 = 0.f, m1 = 0.f, m2 = 0.f;
#pragma unroll
    for (int j = 0; j < 30; ++j) {
      const float av = lg[j] * inv;
      attn_out[(size_t)b * 900 + lane * 30 + j] = av;
      if (j < 10) m0 += av; else if (j < 20) m1 += av; else m2 += av;
    }
    indv[lane] = m0 * 0.1f; indv[30 + lane] = m1 * 0.1f; indv[60 + lane] = m2 * 0.1f;
  }
  __syncthreads();
  if (lane == 0) {
    float best = -1e30f; int bi = 0;
    for (int k = 0; k < 90; ++k) { const float v = indv[k]; if (v > best) { best = v; bi = k; } }
    atomicAdd(ind_sum, (float)bi);
  }
}

// ---------------- K6b: op scalar ----------------
__global__ void k6b_op(float* __restrict__ ind_sum, float* __restrict__ op_out) {
  const float ind = ind_sum[0] * (1.f / 64.f);
  const int op = ind < 0.6f ? 0 : (ind < 1.6f ? 1 : 2);
  ind_sum[1] = (float)op;
  op_out[0] = (float)op;
}

// ---------------- K7a: one = selected branch ----------------
__global__ __launch_bounds__(256) void k7a_one(const float* __restrict__ out1w, const float* __restrict__ out2w,
                                               const float* __restrict__ out3raw, const float* __restrict__ rowsumg,
                                               const float* __restrict__ indws, float* __restrict__ one_out) {
  const int b = blockIdx.x, c = threadIdx.x;
  const int op = (int)indws[1];
  float* dst = one_out + ((size_t)(b * CH + c)) * NP;
  if (op == 0) {
    const float v = out1w[b * CH + c];
#pragma unroll
    for (int p = 0; p < NP; ++p) dst[p] = v;
  } else if (op == 1) {
    const float* s = out2w + ((size_t)(b * CH + c)) * NP;
#pragma unroll
    for (int p = 0; p < NP; ++p) dst[p] = s[p];
  } else {
    const float* s = out3raw + ((size_t)(b * CH + c)) * NP;
#pragma unroll
    for (int p = 0; p < NP; ++p) dst[p] = s[p] / rowsumg[b * 16 + p];
  }
}

// ---------------- K7b: ensemble = concat_out @ attn ----------------
__global__ __launch_bounds__(256) void k7b_ens(const float* __restrict__ out1w, const float* __restrict__ out2w,
                                               const float* __restrict__ out3raw, const float* __restrict__ rowsumg,
                                               const float* __restrict__ attn, float* __restrict__ ens) {
  const int b = blockIdx.x, tid = threadIdx.x;
  __shared__ float at[900];
  __shared__ float s0[30];
  __shared__ float irs[NP];
  for (int k = tid; k < 900; k += 256) at[k] = attn[(size_t)b * 900 + k];
  if (tid < NP) irs[tid] = 1.f / rowsumg[b * 16 + tid];
  __syncthreads();
  if (tid < 30) {
    float s = 0.f;
    for (int i = 0; i < 10; ++i) s += at[i * 30 + tid];
    s0[tid] = s;
  }
  __syncthreads();
  const int c = tid;
  const float o1 = out1w[b * CH + c];
  float o2[NP], o3[NP];
  const float* p2 = out2w + ((size_t)(b * CH + c)) * NP;
  const float* p3 = out3raw + ((size_t)(b * CH + c)) * NP;
#pragma unroll
  for (int p = 0; p < NP; ++p) { o2[p] = p2[p]; o3[p] = p3[p] * irs[p]; }
  float* dst = ens + ((size_t)(b * CH + c)) * 30;
#pragma unroll
  for (int j = 0; j < 30; ++j) {
    float acc = o1 * s0[j];
#pragma unroll
    for (int p = 0; p < NP; ++p) acc += o2[p] * at[(10 + p) * 30 + j] + o3[p] * at[(20 + p) * 30 + j];
    dst[j] = acc;
  }
}

// ---------------- K7c: z1 partial GEMM (one[64x2560] @ w1^T -> [64x512]) ----------------
__global__ __launch_bounds__(256) void k7c_z1(const float* __restrict__ one_, const float* __restrict__ w1,
                                              float* __restrict__ z1acc) {
  const int kt = blockIdx.x;  // 8
  const int mt = blockIdx.y;  // 40
  const int tid = threadIdx.x;
  __shared__ float os[64][65];
  __shared__ float wsl[64][65];
  const int k0 = kt * 64, m0 = mt * 64;
#pragma unroll
  for (int k = 0; k < 4; ++k) {
    int idx = tid + k * 256;
    int r = idx >> 4, q = (idx & 15) * 4;
    float4 v1 = *(const float4*)(one_ + (size_t)r * 2560 + m0 + q);
    os[r][q] = v1.x; os[r][q + 1] = v1.y; os[r][q + 2] = v1.z; os[r][q + 3] = v1.w;
    float4 v2 = *(const float4*)(w1 + (size_t)(k0 + r) * 2560 + m0 + q);
    wsl[r][q] = v2.x; wsl[r][q + 1] = v2.y; wsl[r][q + 2] = v2.z; wsl[r][q + 3] = v2.w;
  }
  __syncthreads();
  const int bg = tid >> 4, kg = tid & 15;
  float acc[4][4];
#pragma unroll
  for (int i = 0; i < 4; ++i)
#pragma unroll
    for (int j = 0; j < 4; ++j) acc[i][j] = 0.f;
  for (int m = 0; m < 64; ++m) {
    float ov[4], wv[4];
#pragma unroll
    for (int i = 0; i < 4; ++i) { ov[i] = os[bg * 4 + i][m]; wv[i] = wsl[kg * 4 + i][m]; }
#pragma unroll
    for (int i = 0; i < 4; ++i)
#pragma unroll
      for (int j = 0; j < 4; ++j) acc[i][j] += ov[i] * wv[j];
  }
#pragma unroll
  for (int i = 0; i < 4; ++i)
#pragma unroll
    for (int j = 0; j < 4; ++j)
      atomicAdd(&z1acc[(size_t)(bg * 4 + i) * 512 + k0 + kg * 4 + j], acc[i][j]);
}

// ---------------- K7d: z2 partial GEMM (relu(z1+b1)[64x512] @ w2^T -> [64x1024]) ----------------
__global__ __launch_bounds__(256) void k7d_z2(const float* __restrict__ z1acc, const float* __restrict__ db1,
                                              const float* __restrict__ w2, float* __restrict__ z2acc) {
  const int kt = blockIdx.x;  // 16
  const int mt = blockIdx.y;  // 8
  const int tid = threadIdx.x;
  __shared__ float os[64][65];
  __shared__ float wsl[64][65];
  const int k0 = kt * 64, m0 = mt * 64;
#pragma unroll
  for (int k = 0; k < 4; ++k) {
    int idx = tid + k * 256;
    int r = idx >> 4, q = (idx & 15) * 4;
    float4 v1 = *(const float4*)(z1acc + (size_t)r * 512 + m0 + q);
    float4 bv = *(const float4*)(db1 + m0 + q);
    os[r][q] = fmaxf(v1.x + bv.x, 0.f); os[r][q + 1] = fmaxf(v1.y + bv.y, 0.f);
    os[r][q + 2] = fmaxf(v1.z + bv.z, 0.f); os[r][q + 3] = fmaxf(v1.w + bv.w, 0.f);
    float4 v2 = *(const float4*)(w2 + (size_t)(k0 + r) * 512 + m0 + q);
    wsl[r][q] = v2.x; wsl[r][q + 1] = v2.y; wsl[r][q + 2] = v2.z; wsl[r][q + 3] = v2.w;
  }
  __syncthreads();
  const int bg = tid >> 4, kg = tid & 15;
  float acc[4][4];
#pragma unroll
  for (int i = 0; i < 4; ++i)
#pragma unroll
    for (int j = 0; j < 4; ++j) acc[i][j] = 0.f;
  for (int m = 0; m < 64; ++m) {
    float ov[4], wv[4];
#pragma unroll
    for (int i = 0; i < 4; ++i) { ov[i] = os[bg * 4 + i][m]; wv[i] = wsl[kg * 4 + i][m]; }
#pragma unroll
    for (int i = 0; i < 4; ++i)
#pragma unroll
      for (int j = 0; j < 4; ++j) acc[i][j] += ov[i] * wv[j];
  }
#pragma unroll
  for (int i = 0; i < 4; ++i)
#pragma unroll
    for (int j = 0; j < 4; ++j)
      atomicAdd(&z2acc[(size_t)(bg * 4 + i) * 1024 + k0 + kg * 4 + j], acc[i][j]);
}

// ---------------- K7e: out = relu(z2+b2) @ w3^T + b3 ----------------
__global__ __launch_bounds__(64) void k7e_out(const float* __restrict__ z2acc, const float* __restrict__ db2,
                                              const float* __restrict__ w3, const float* __restrict__ db3,
                                              float* __restrict__ outp) {
  const int b = blockIdx.x, lane = threadIdx.x;
  float acc[NP];
#pragma unroll
  for (int n = 0; n < NP; ++n) acc[n] = 0.f;
  for (int j = lane; j < 1024; j += 64) {
    float zv = z2acc[(size_t)b * 1024 + j] + db2[j];
    zv = fmaxf(zv, 0.f);
#pragma unroll
    for (int n = 0; n < NP; ++n) acc[n] += zv * w3[(size_t)n * 1024 + j];
  }
#pragma unroll
  for (int n = 0; n < NP; ++n)
#pragma unroll
    for (int st = 32; st >= 1; st >>= 1) acc[n] += __shfl_xor(acc[n], st);
  if (lane == 0) {
#pragma unroll
    for (int n = 0; n < NP; ++n) outp[b * NP + n] = acc[n] + db3[n];
  }
}

// ---------------- launch ----------------
extern "C" void kernel_launch(void* const* d_in, const int* in_sizes, int n_in,
                              void* d_out, int out_size, void* d_ws, size_t ws_size,
                              hipStream_t stream) {
  (void)in_sizes; (void)n_in; (void)out_size; (void)ws_size;
  const float* x      = (const float*)d_in[0];
  const float* conv_w = (const float*)d_in[1];
  const float* conv_b = (const float*)d_in[2];
  const float* protos = (const float*)d_in[3];
  const float* sw     = (const float*)d_in[4];
  const float* enc_w  = (const float*)d_in[5];
  const float* enc_b  = (const float*)d_in[6];
  const float* dw1    = (const float*)d_in[7];
  const float* db1    = (const float*)d_in[8];
  const float* dw2    = (const float*)d_in[9];
  const float* db2    = (const float*)d_in[10];
  const float* dw3    = (const float*)d_in[11];
  const float* db3    = (const float*)d_in[12];
  float* out = (float*)d_out;
  float* ws  = (float*)d_ws;

  float* D2g     = ws + OFF_D2;
  float* Yg      = ws + OFF_Y;
  float* Ag      = ws + OFF_A;
  float* rowsumg = ws + OFF_RS;
  float* out1w   = ws + OFF_O1;
  float* out2w   = ws + OFF_O2;
  float* out3raw = ws + OFF_O3;
  float* indws   = ws + OFF_IND;
  float* z1acc   = ws + OFF_Z1;
  float* z2acc   = ws + OFF_Z2;
  float* h       = out + DO_H;

  // zero the atomic accumulators (out3raw, ind, z1acc, z2acc)
  hipMemsetAsync(ws + OFF_O3, 0, (WS_END - OFF_O3) * sizeof(float), stream);

  k1_conv<<<dim3(16, 4, 64), 256, 0, stream>>>(x, conv_w, conv_b, h);
  k2_d2<<<dim3(8, 64), 256, 0, stream>>>(h, protos, D2g);
  k3a_seg<<<dim3(10, 256, 64), 64, 0, stream>>>(h, out2w);
  k3b_fin<<<64, 256, 0, stream>>>(out2w, out1w);
  k4_dp<<<64, 64, 0, stream>>>(D2g, Yg, Ag, rowsumg);
  k5_out3<<<dim3(16, 64), 256, 0, stream>>>(h, Ag, out3raw);
  k6a_head<<<64, 64, 0, stream>>>(out1w, out2w, out3raw, rowsumg, enc_w, enc_b, sw,
                                  out + DO_ATT, indws);
  k6b_op<<<1, 1, 0, stream>>>(indws, out + DO_OP);
  k7a_one<<<64, 256, 0, stream>>>(out1w, out2w, out3raw, rowsumg, indws, out + DO_ONE);
  k7b_ens<<<64, 256, 0, stream>>>(out1w, out2w, out3raw, rowsumg, out + DO_ATT, out + DO_ENS);
  k7c_z1<<<dim3(8, 40), 256, 0, stream>>>(out + DO_ONE, dw1, z1acc);
  k7d_z2<<<dim3(16, 8), 256, 0, stream>>>(z1acc, db1, dw2, z2acc);
  k7e_out<<<64, 64, 0, stream>>>(z2acc, db2, dw3, db3, out + DO_OUT);
}